// Round 1
// baseline (953.745 us; speedup 1.0000x reference)
//
#include <hip/hip_runtime.h>
#include <math.h>

// Problem dims (fixed by reference)
#define B_SZ   2048
#define L_SEQ  128
#define C_INCH 150
#define H_OUT  230
#define HP     256     // Wt padded H (zeros for h>=230)
#define C_CHUNK 75     // channels staged per LDS pass (2 passes)
#define ROWP   132     // LDS row stride in floats; %4==0 -> 16B-aligned float4

// Pack W[h][c][k] (h*450 + c*3 + k) -> Wt[(c*3+k)*HP + h], zero for h>=H_OUT.
// Runs every launch (ws is re-poisoned each call).
__global__ void pack_w_kernel(const float* __restrict__ W, float* __restrict__ Wt) {
    int idx = blockIdx.x * 256 + threadIdx.x;       // 450*256 = 115200 exact
    int h = idx & (HP - 1);
    int r = idx >> 8;                               // 0..449 == c*3+k
    int c = r / 3;
    int k = r - c * 3;
    float v = (h < H_OUT) ? W[(h * C_INCH + c) * 3 + k] : 0.0f;
    Wt[idx] = v;
}

__global__ void __launch_bounds__(256)
pcnn_kernel(const float* __restrict__ Xea, const int* __restrict__ Xmask,
            const float* __restrict__ Wt, const float* __restrict__ bias,
            float* __restrict__ out) {
    // LDS: X chunk transposed, sX[cc][col] with col = l+1 (halo zeros at col 0, 129)
    __shared__ __align__(16) float sX[C_CHUNK * ROWP];  // 39600 B
    __shared__ int sM[L_SEQ];

    const int b    = blockIdx.x;
    const int hblk = blockIdx.y;                 // 0..3, 64 h each
    const int tid  = threadIdx.x;
    const int tx   = tid & 15;                   // l-group: 8 l's each
    const int ty   = tid >> 4;                   // h-group: 4 consecutive h
    const int h0   = hblk * 64 + ty * 4;         // < 256 (Wt padded)
    const int l0   = tx * 8;

    if (tid < L_SEQ) sM[tid] = Xmask[b * L_SEQ + tid];

    float acc[4][8];
    #pragma unroll
    for (int i = 0; i < 4; ++i)
        #pragma unroll
        for (int j = 0; j < 8; ++j) acc[i][j] = 0.0f;

    const float* xb = Xea + (size_t)b * (L_SEQ * C_INCH);

    for (int c0 = 0; c0 < C_INCH; c0 += C_CHUNK) {
        __syncthreads();   // protect previous chunk's reads
        // Stage: coalesced global reads (runs of 75 consecutive floats per l)
        for (int t = tid; t < C_CHUNK * L_SEQ; t += 256) {
            int l  = t / C_CHUNK;
            int cc = t - l * C_CHUNK;
            sX[cc * ROWP + 1 + l] = xb[l * C_INCH + (c0 + cc)];
        }
        for (int cc = tid; cc < C_CHUNK; cc += 256) {
            sX[cc * ROWP + 0]   = 0.0f;   // l = -1 pad
            sX[cc * ROWP + 129] = 0.0f;   // l = 128 pad
        }
        __syncthreads();

        const float* wp = Wt + (size_t)(c0 * 3) * HP + h0;
        unsigned xoff = (unsigned)l0;
        #pragma unroll 2
        for (int cc = 0; cc < C_CHUNK; ++cc) {
            const float4 w0 = *(const float4*)(wp);            // k=0, 4 h's
            const float4 w1 = *(const float4*)(wp + HP);       // k=1
            const float4 w2 = *(const float4*)(wp + 2 * HP);   // k=2
            const float4 xA = *(const float4*)(&sX[xoff]);
            const float4 xB = *(const float4*)(&sX[xoff + 4]);
            const float4 xC = *(const float4*)(&sX[xoff + 8]);
            float x[12] = {xA.x, xA.y, xA.z, xA.w,
                           xB.x, xB.y, xB.z, xB.w,
                           xC.x, xC.y, xC.z, xC.w};
            float wk[3][4] = {{w0.x, w0.y, w0.z, w0.w},
                              {w1.x, w1.y, w1.z, w1.w},
                              {w2.x, w2.y, w2.z, w2.w}};
            #pragma unroll
            for (int k = 0; k < 3; ++k) {
                #pragma unroll
                for (int i = 0; i < 4; ++i) {
                    const float wv = wk[k][i];
                    #pragma unroll
                    for (int j = 0; j < 8; ++j)
                        acc[i][j] = fmaf(wv, x[j + k], acc[i][j]);
                }
            }
            wp += 3 * HP;
            xoff += ROWP;
        }
    }

    // Epilogue: bias + masked piecewise max + tanh
    float bv[4];
    #pragma unroll
    for (int i = 0; i < 4; ++i) {
        int h = h0 + i;
        bv[i] = (h < H_OUT) ? bias[h] : 0.0f;
    }

    float pmax[4][3];
    #pragma unroll
    for (int i = 0; i < 4; ++i)
        #pragma unroll
        for (int p = 0; p < 3; ++p) pmax[i][p] = 0.0f;  // 0-products always present

    #pragma unroll
    for (int j = 0; j < 8; ++j) {
        const int mv = sM[l0 + j];
        #pragma unroll
        for (int i = 0; i < 4; ++i) {
            const float y = acc[i][j] + bv[i];
            #pragma unroll
            for (int p = 0; p < 3; ++p) {
                const float cand = (mv == p + 1) ? y : 0.0f;
                pmax[i][p] = fmaxf(pmax[i][p], cand);
            }
        }
    }

    // Reduce across the 16 l-group lanes (tx lives in lane bits 0..3)
    #pragma unroll
    for (int off = 8; off >= 1; off >>= 1) {
        #pragma unroll
        for (int i = 0; i < 4; ++i)
            #pragma unroll
            for (int p = 0; p < 3; ++p)
                pmax[i][p] = fmaxf(pmax[i][p], __shfl_xor(pmax[i][p], off, 64));
    }

    if (tx == 0) {
        #pragma unroll
        for (int i = 0; i < 4; ++i) {
            const int h = h0 + i;
            if (h < H_OUT) {
                float* o = out + (size_t)b * (3 * H_OUT) + h * 3;
                #pragma unroll
                for (int p = 0; p < 3; ++p) o[p] = tanhf(pmax[i][p]);
            }
        }
    }
}

extern "C" void kernel_launch(void* const* d_in, const int* in_sizes, int n_in,
                              void* d_out, int out_size, void* d_ws, size_t ws_size,
                              hipStream_t stream) {
    const float* Xea   = (const float*)d_in[0];   // [2048,128,150] f32
    const int*   Xmask = (const int*)d_in[1];     // [2048,128] i32
    const float* W     = (const float*)d_in[2];   // [230,150,3] f32
    const float* bias  = (const float*)d_in[3];   // [230] f32
    float* out = (float*)d_out;                   // [2048, 690] f32
    float* Wt  = (float*)d_ws;                    // 450*256 floats = 460800 B

    pack_w_kernel<<<450, 256, 0, stream>>>(W, Wt);
    dim3 grid(B_SZ, 4);
    pcnn_kernel<<<grid, 256, 0, stream>>>(Xea, Xmask, Wt, bias, out);
}

// Round 2
// 340.245 us; speedup vs baseline: 2.8031x; 2.8031x over previous
//
#include <hip/hip_runtime.h>
#include <math.h>

// PCNN fused: Conv1d(k=3,pad=1) -> masked piecewise max-pool -> tanh
// MFMA bf16 formulation: per block = one batch element b.
//   Y[l,h] = sum_k sum_c X[b,l+k-1,c] * W[h,c,k]
// = 3 shifted GEMMs over one LDS-resident X[b] tile (bf16).
// M=128 (l), N=256 (h padded from 230), K=3*160 (c padded from 150).

#define B_SZ   2048
#define L_SEQ  128
#define C_INCH 150
#define H_OUT  230
#define HPAD   256      // padded h
#define CPAD   160      // padded channels per shift
#define KW     480      // Wbf row length = 3*CPAD (bf16)
#define RS     168      // LDS X row stride in bf16 (336 B = 21*16 -> all rows 16B aligned)

typedef __attribute__((ext_vector_type(8))) short short8;   // 8 bf16 = 4 VGPRs
typedef __attribute__((ext_vector_type(4))) float float4v;  // mfma acc

static __device__ __forceinline__ unsigned short f2bf(float f) {
    union { float f; unsigned u; } x{f};
    unsigned r = (x.u + 0x7FFFu + ((x.u >> 16) & 1u)) >> 16;  // RNE
    return (unsigned short)r;
}

// Pack W[h][c][k] (fp32) -> Wbf[h][k*CPAD + c] (bf16), zero-padded.
// 256x480 elems = 480 blocks x 256 threads.
__global__ void pack_w_kernel(const float* __restrict__ W,
                              unsigned short* __restrict__ Wbf) {
    int idx = blockIdx.x * 256 + threadIdx.x;   // < HPAD*KW = 122880
    int h  = idx / KW;
    int kk = idx - h * KW;
    int k  = kk / CPAD;
    int c  = kk - k * CPAD;
    float v = (h < H_OUT && c < C_INCH) ? W[h * 450 + c * 3 + k] : 0.0f;
    Wbf[idx] = f2bf(v);
}

__global__ void __launch_bounds__(256, 2)
pcnn_mfma_kernel(const float* __restrict__ Xea, const int* __restrict__ Xmask,
                 const unsigned short* __restrict__ Wbf,
                 const float* __restrict__ bias, float* __restrict__ out) {
    // LDS: X[b] in bf16, rows = l+1 for l in [-1,128], 130 rows x RS
    __shared__ __align__(16) unsigned char smem[130 * RS * 2 + 512];
    unsigned short* sX = (unsigned short*)smem;
    int* sM = (int*)(smem + 130 * RS * 2);

    const int b    = blockIdx.x;
    const int tid  = threadIdx.x;
    const int wv   = tid >> 6;        // wave 0..3 -> h slice [64*wv, 64*wv+64)
    const int lane = tid & 63;
    const int q    = lane >> 4;       // quad 0..3
    const int c15  = lane & 15;

    const float* xb = Xea + (size_t)b * (L_SEQ * C_INCH);

    // ---- Stage X[b] fp32 -> bf16 LDS (float2-granular, coalesced) ----
    for (int t = tid; t < (L_SEQ * C_INCH) / 2; t += 256) {   // 9600
        int l  = t / 75;
        int c2 = (t - l * 75) * 2;
        const float2 v = *(const float2*)(xb + l * C_INCH + c2);
        unsigned short* p = sX + (l + 1) * RS + c2;
        p[0] = f2bf(v.x);
        p[1] = f2bf(v.y);
    }
    // halo rows l=-1 (row 0) and l=128 (row 129): zero
    for (int t = tid; t < 2 * RS; t += 256) {
        int row = (t < RS) ? 0 : 129;
        sX[row * RS + (t % RS)] = 0;
    }
    // channel pad c in [150,160) for rows 1..128
    for (int t = tid; t < 128 * (CPAD - C_INCH); t += 256) {
        int r = t / (CPAD - C_INCH);
        int c = C_INCH + (t - r * (CPAD - C_INCH));
        sX[(r + 1) * RS + c] = 0;
    }
    if (tid < L_SEQ) sM[tid] = Xmask[(size_t)b * L_SEQ + tid];
    __syncthreads();

    // ---- MFMA main loop: 3 shifts x 5 k-chunks, no barriers ----
    float4v acc[8][4];
    #pragma unroll
    for (int mi = 0; mi < 8; ++mi)
        #pragma unroll
        for (int nj = 0; nj < 4; ++nj)
            acc[mi][nj] = (float4v){0.f, 0.f, 0.f, 0.f};

    const unsigned short* wrow = Wbf + (size_t)(wv * 64 + c15) * KW + q * 8;

    for (int k = 0; k < 3; ++k) {
        #pragma unroll
        for (int kc = 0; kc < 5; ++kc) {
            // A frags: A[m = c15][kdim = q*8+j], m-frag mi covers l = mi*16 + c15,
            // shifted row = l + k (row index = l' + 1 = l + k - 1 + 1)
            short8 a[8];
            #pragma unroll
            for (int mi = 0; mi < 8; ++mi)
                a[mi] = *(const short8*)(sX + (mi * 16 + c15 + k) * RS + kc * 32 + q * 8);
            // B frags: B[n = c15][kdim = q*8+j] from Wbf row h = wv*64 + nj*16 + c15
            short8 bf[4];
            #pragma unroll
            for (int nj = 0; nj < 4; ++nj)
                bf[nj] = *(const short8*)(wrow + nj * 16 * KW + k * CPAD + kc * 32);
            #pragma unroll
            for (int mi = 0; mi < 8; ++mi)
                #pragma unroll
                for (int nj = 0; nj < 4; ++nj)
                    acc[mi][nj] = __builtin_amdgcn_mfma_f32_16x16x32_bf16(
                        a[mi], bf[nj], acc[mi][nj], 0, 0, 0);
        }
    }

    // ---- Epilogue: bias + masked piecewise max over l + tanh ----
    // C/D layout: col(n=h) = lane&15, row(m=l within frag) = q*4 + r
    #pragma unroll
    for (int nj = 0; nj < 4; ++nj) {
        const int h = wv * 64 + nj * 16 + c15;
        const float bh = (h < H_OUT) ? bias[h] : 0.0f;
        float p0 = 0.f, p1 = 0.f, p2 = 0.f;   // zero-product always present per piece
        #pragma unroll
        for (int mi = 0; mi < 8; ++mi) {
            #pragma unroll
            for (int r = 0; r < 4; ++r) {
                const int l = mi * 16 + q * 4 + r;
                const int mv = sM[l];
                const float y = acc[mi][nj][r] + bh;
                p0 = fmaxf(p0, (mv == 1) ? y : 0.0f);
                p1 = fmaxf(p1, (mv == 2) ? y : 0.0f);
                p2 = fmaxf(p2, (mv == 3) ? y : 0.0f);
            }
        }
        // reduce over q (lane bits 4,5) -> full max over all 128 l
        p0 = fmaxf(p0, __shfl_xor(p0, 16, 64));
        p1 = fmaxf(p1, __shfl_xor(p1, 16, 64));
        p2 = fmaxf(p2, __shfl_xor(p2, 16, 64));
        p0 = fmaxf(p0, __shfl_xor(p0, 32, 64));
        p1 = fmaxf(p1, __shfl_xor(p1, 32, 64));
        p2 = fmaxf(p2, __shfl_xor(p2, 32, 64));
        if (q == 0 && h < H_OUT) {
            float* o = out + (size_t)b * (3 * H_OUT) + h * 3;
            o[0] = tanhf(p0);
            o[1] = tanhf(p1);
            o[2] = tanhf(p2);
        }
    }
}

extern "C" void kernel_launch(void* const* d_in, const int* in_sizes, int n_in,
                              void* d_out, int out_size, void* d_ws, size_t ws_size,
                              hipStream_t stream) {
    const float* Xea   = (const float*)d_in[0];   // [2048,128,150] f32
    const int*   Xmask = (const int*)d_in[1];     // [2048,128] i32
    const float* W     = (const float*)d_in[2];   // [230,150,3] f32
    const float* bias  = (const float*)d_in[3];   // [230] f32
    float* out = (float*)d_out;                   // [2048,690] f32
    unsigned short* Wbf = (unsigned short*)d_ws;  // 256*480*2 = 245760 B

    pack_w_kernel<<<(HPAD * KW) / 256, 256, 0, stream>>>(W, Wbf);
    pcnn_mfma_kernel<<<B_SZ, 256, 0, stream>>>(Xea, Xmask, Wbf, bias, out);
}